// Round 1
// baseline (694.080 us; speedup 1.0000x reference)
//
#include <hip/hip_runtime.h>
#include <stdint.h>
#include <stddef.h>

typedef __bf16 bf16;
typedef __attribute__((ext_vector_type(8))) __bf16 bf16x8;
typedef __attribute__((ext_vector_type(4))) __bf16 bf16x4;
typedef __attribute__((ext_vector_type(4))) float f32x4;

#define NN 4096
#define HIDD 512
#define NE 65536

// ---------- async global->LDS, 16B per lane, wave-uniform LDS base ----------
__device__ inline void gll16(const void* g, void* l) {
    __builtin_amdgcn_global_load_lds(
        (const __attribute__((address_space(1))) void*)g,
        (__attribute__((address_space(3))) void*)l, 16, 0, 0);
}

// ---------- fp32 -> bf16 elementwise convert (n multiple of 1024) ----------
__global__ void cvt_f32_bf16(const float* __restrict__ in, bf16* __restrict__ out, int n) {
    int i = (blockIdx.x * 256 + threadIdx.x) * 4;
    if (i >= n) return;
    float4 v = *reinterpret_cast<const float4*>(in + i);
    bf16x4 o;
    o[0] = (bf16)v.x; o[1] = (bf16)v.y; o[2] = (bf16)v.z; o[3] = (bf16)v.w;
    *reinterpret_cast<bf16x4*>(out + i) = o;
}

// ---------- sum S bf16 slices of n elems -> bf16 (n multiple of 2048) ----------
__global__ void reduce_bf16_slices(const bf16* __restrict__ in, bf16* __restrict__ out,
                                   int n, int S) {
    int i = (blockIdx.x * 256 + threadIdx.x) * 8;
    if (i >= n) return;
    float acc[8] = {};
    for (int k = 0; k < S; ++k) {
        bf16x8 v = *reinterpret_cast<const bf16x8*>(in + (size_t)k * n + i);
#pragma unroll
        for (int j = 0; j < 8; ++j) acc[j] += (float)v[j];
    }
    bf16x8 o;
#pragma unroll
    for (int j = 0; j < 8; ++j) o[j] = (bf16)acc[j];
    *reinterpret_cast<bf16x8*>(out + i) = o;
}

// ---------- fp32 transpose -> bf16 with column zero-padding: out[c][r] = in[r][c] ----------
__global__ void transpose_pad_f32(const float* __restrict__ in, bf16* __restrict__ out,
                                  int R, int C, int Cpad) {
    __shared__ bf16 tile[32][33];
    int c0 = blockIdx.x * 32, r0 = blockIdx.y * 32;
    int tx = threadIdx.x, ty = threadIdx.y;
    for (int i = ty; i < 32; i += 8) {
        int r = r0 + i, c = c0 + tx;
        bf16 v = (bf16)0.f;
        if (r < R && c < C) v = (bf16)in[(size_t)r * C + c];
        tile[i][tx] = v;
    }
    __syncthreads();
    for (int i = ty; i < 32; i += 8) {
        int oc = c0 + i, orow = r0 + tx;
        if (oc < Cpad && orow < R) out[(size_t)oc * R + orow] = tile[tx][i];
    }
}

// ---------- fp32 square matrix: one read of in, write both bf16(in^T) and bf16(in) ----------
__global__ void transpose_dual_f32(const float* __restrict__ in, bf16* __restrict__ outT,
                                   bf16* __restrict__ outD, int Nn) {
    __shared__ bf16 tile[32][33];
    int c0 = blockIdx.x * 32, r0 = blockIdx.y * 32;
    int tx = threadIdx.x, ty = threadIdx.y;
    for (int i = ty; i < 32; i += 8) {
        int r = r0 + i, c = c0 + tx;
        bf16 v = (bf16)in[(size_t)r * Nn + c];
        tile[i][tx] = v;
        outD[(size_t)r * Nn + c] = v;
    }
    __syncthreads();
    for (int i = ty; i < 32; i += 8)
        outT[(size_t)(c0 + i) * Nn + r0 + tx] = tile[tx][i];
}

// ---------- bf16 transpose: out[c][r] = in[r][c], dims multiple of 32 ----------
__global__ void transpose_bf16(const bf16* __restrict__ in, bf16* __restrict__ out,
                               int R, int C) {
    __shared__ bf16 tile[32][33];
    int c0 = blockIdx.x * 32, r0 = blockIdx.y * 32;
    int tx = threadIdx.x, ty = threadIdx.y;
    for (int i = ty; i < 32; i += 8)
        tile[i][tx] = in[(size_t)(r0 + i) * C + c0 + tx];
    __syncthreads();
    for (int i = ty; i < 32; i += 8)
        out[(size_t)(c0 + i) * R + r0 + tx] = tile[tx][i];
}

// ---------- NT GEMM: C[M,N] = A[M,K] * B[N,K]^T, m97 structure ----------
// OMODE: 0 = fp32 out at Cp + z*M*N; 1 = bf16 out; 2 = bf16 partial at Cp + z*M*N
template<int OMODE, bool HAS_BIAS, bool ROW_SCALE>
__global__ __launch_bounds__(256)
void gemm_nt(const bf16* __restrict__ A, const bf16* __restrict__ B,
             void* __restrict__ Cp, const float* __restrict__ bias,
             const float* __restrict__ rowscale, int M, int N, int K) {
    __shared__ __align__(16) bf16 As[128 * 32];
    __shared__ __align__(16) bf16 Bs[128 * 32];
    const int tid  = threadIdx.x;
    const int wave = tid >> 6;
    const int lane = tid & 63;
    const int m0 = blockIdx.y * 128, n0 = blockIdx.x * 128;
    const int lrow = lane >> 2;
    const int lcol = (lane & 3) * 8;
    const int c0 = wave * 2;
    const size_t arow0 = (size_t)(m0 + c0 * 16 + lrow) * K + lcol;
    const size_t arow1 = (size_t)(m0 + (c0 + 1) * 16 + lrow) * K + lcol;
    const size_t brow0 = (size_t)(n0 + c0 * 16 + lrow) * K + lcol;
    const size_t brow1 = (size_t)(n0 + (c0 + 1) * 16 + lrow) * K + lcol;
    bf16* asd0 = &As[c0 * 512];
    bf16* asd1 = &As[(c0 + 1) * 512];
    bf16* bsd0 = &Bs[c0 * 512];
    bf16* bsd1 = &Bs[(c0 + 1) * 512];

    f32x4 acc[4][4] = {};

    const int wm = (wave >> 1) * 64;
    const int wn = (wave & 1) * 64;
    const int fm = wm + (lane & 15);
    const int fn = wn + (lane & 15);
    const int fk = (lane >> 4) * 8;

    const int kper = K / gridDim.z;
    const int kz0 = blockIdx.z * kper;
    const int kz1 = kz0 + kper;

    for (int k0 = kz0; k0 < kz1; k0 += 32) {
        gll16(A + arow0 + k0, asd0);
        gll16(A + arow1 + k0, asd1);
        gll16(B + brow0 + k0, bsd0);
        gll16(B + brow1 + k0, bsd1);
        __syncthreads();
        bf16x8 af[4], bg[4];
#pragma unroll
        for (int i = 0; i < 4; ++i)
            af[i] = *reinterpret_cast<const bf16x8*>(&As[(fm + i * 16) * 32 + fk]);
#pragma unroll
        for (int j = 0; j < 4; ++j)
            bg[j] = *reinterpret_cast<const bf16x8*>(&Bs[(fn + j * 16) * 32 + fk]);
#pragma unroll
        for (int i = 0; i < 4; ++i)
#pragma unroll
            for (int j = 0; j < 4; ++j)
                acc[i][j] = __builtin_amdgcn_mfma_f32_16x16x32_bf16(af[i], bg[j], acc[i][j], 0, 0, 0);
        __syncthreads();
    }

    const int rbase = m0 + wm + (lane >> 4) * 4;
    const int cbase = n0 + wn + (lane & 15);
    float* outf = (float*)Cp + (size_t)blockIdx.z * M * N;
    bf16*  outb = (bf16*)Cp;
    bf16*  outp = (bf16*)Cp + (size_t)blockIdx.z * M * N;
#pragma unroll
    for (int i = 0; i < 4; ++i) {
#pragma unroll
        for (int j = 0; j < 4; ++j) {
            int col = cbase + j * 16;
            float bv = 0.f;
            if (HAS_BIAS) bv = bias[col];
#pragma unroll
            for (int r = 0; r < 4; ++r) {
                int row = rbase + i * 16 + r;
                float v = acc[i][j][r];
                if (ROW_SCALE) v *= rowscale[row];
                v += bv;
                if (OMODE == 0)      outf[(size_t)row * N + col] = v;
                else if (OMODE == 1) outb[(size_t)row * N + col] = (bf16)v;
                else                 outp[(size_t)row * N + col] = (bf16)v;
            }
        }
    }
}

// ---------- colnorm partials: n2[i] += sum_{a in chunk} (Rf0+Rf1)[a,i]*Ht[a,i] ----------
__global__ void colnorm_part(const bf16* __restrict__ Ht, const float* __restrict__ Rf,
                             float* __restrict__ n2) {
    int i = blockIdx.x * 128 + threadIdx.x;   // 32 x-blocks cover 4096 cols
    int a0 = blockIdx.y * 64;                 // 8 y-blocks cover 512 rows
    const float* Rf2 = Rf + (size_t)HIDD * NN;
    float s = 0.f;
    for (int a = a0; a < a0 + 64; ++a) {
        size_t idx = (size_t)a * NN + i;
        s += (Rf[idx] + Rf2[idx]) * (float)Ht[idx];
    }
    atomicAdd(&n2[i], s);
}

__global__ void colnorm_fin(const float* __restrict__ n2, float* __restrict__ inv) {
    int i = blockIdx.x * 256 + threadIdx.x;
    inv[i] = 1.f / fmaxf(sqrtf(n2[i]), 1e-12f);
}

// ---------- b' = W1 @ b0 + b1  (one wave per row) ----------
__global__ void bias_fuse(const float* __restrict__ W1, const float* __restrict__ b0,
                          const float* __restrict__ b1, float* __restrict__ bp) {
    int row = blockIdx.x * 4 + (threadIdx.x >> 6);
    int lane = threadIdx.x & 63;
    const float4* wr = (const float4*)(W1 + (size_t)row * HIDD);
    const float4* bz = (const float4*)b0;
    float s = 0.f;
#pragma unroll
    for (int j = 0; j < 2; ++j) {
        float4 a = wr[lane * 2 + j], b = bz[lane * 2 + j];
        s += a.x * b.x + a.y * b.y + a.z * b.z + a.w * b.w;
    }
    for (int off = 32; off; off >>= 1) s += __shfl_down(s, off);
    if (lane == 0) bp[row] = b1[row] + s;
}

// ---------- reduce 2 bf16 slices + rowscale + colbias -> bf16 (h epilogue) ----------
__global__ void reduce2_scale_bias(const bf16* __restrict__ p, bf16* __restrict__ out,
                                   const float* __restrict__ inv, const float* __restrict__ bp) {
    int i = (blockIdx.x * 256 + threadIdx.x) * 8;
    const int n = NN * HIDD;
    bf16x8 a = *reinterpret_cast<const bf16x8*>(p + i);
    bf16x8 b = *reinterpret_cast<const bf16x8*>(p + n + i);
    int row = i >> 9;           // HIDD = 512
    int col = i & (HIDD - 1);
    float sc = inv[row];
    bf16x8 o;
#pragma unroll
    for (int j = 0; j < 8; ++j)
        o[j] = (bf16)(((float)a[j] + (float)b[j]) * sc + bp[col + j]);
    *reinterpret_cast<bf16x8*>(out + i) = o;
}

// ---------- CSR build ----------
__global__ void csr_count(const int* __restrict__ ei, int* __restrict__ cnt, int E) {
    int e = blockIdx.x * 256 + threadIdx.x;
    if (e < E) atomicAdd(&cnt[ei[e]], 1);
}

__global__ void scan_4096(const int* __restrict__ cnt, int* __restrict__ rs) {
    __shared__ int s[1024];
    int t = threadIdx.x;
    int b = t * 4;
    int a0 = cnt[b], a1 = cnt[b + 1], a2 = cnt[b + 2], a3 = cnt[b + 3];
    int tot = a0 + a1 + a2 + a3;
    s[t] = tot;
    __syncthreads();
    for (int off = 1; off < 1024; off <<= 1) {
        int v = (t >= off) ? s[t - off] : 0;
        __syncthreads();
        s[t] += v;
        __syncthreads();
    }
    int excl = s[t] - tot;
    rs[b] = excl; rs[b + 1] = excl + a0; rs[b + 2] = excl + a0 + a1; rs[b + 3] = excl + a0 + a1 + a2;
    if (t == 1023) rs[4096] = s[1023];
}

__global__ void csr_scatter(const int* __restrict__ ei, const float* __restrict__ ew,
                            int* __restrict__ cur, int* __restrict__ ccol,
                            float* __restrict__ cw, int E) {
    int e = blockIdx.x * 256 + threadIdx.x;
    if (e < E) {
        int r = ei[e];
        int p = atomicAdd(&cur[r], 1);
        ccol[p] = ei[E + e];
        cw[p] = ew[e];
    }
}

// ---------- one Euler diffusion step in bf16: x' = x + alpha*(Ax - x) + beta*x0 ----------
__global__ void ode_step_bf16(const bf16* __restrict__ xin, const bf16* __restrict__ x0,
                              bf16* __restrict__ xout, const int* __restrict__ rs,
                              const int* __restrict__ ccol, const float* __restrict__ cw,
                              const float* __restrict__ alpha_p, const float* __restrict__ beta_p) {
    int row = blockIdx.x * 4 + (threadIdx.x >> 6);
    int lane = threadIdx.x & 63;
    float alpha = 1.f / (1.f + expf(-alpha_p[0]));
    float beta = beta_p[0];
    const bf16x8* xin8 = (const bf16x8*)xin;
    float acc[8] = {};
    int p0 = rs[row], p1 = rs[row + 1];
    for (int p = p0; p < p1; ++p) {
        int c = ccol[p]; float w = cw[p];
        bf16x8 v = xin8[(size_t)c * 64 + lane];
#pragma unroll
        for (int j = 0; j < 8; ++j) acc[j] += w * (float)v[j];
    }
    bf16x8 xi = xin8[(size_t)row * 64 + lane];
    bf16x8 xz = ((const bf16x8*)x0)[(size_t)row * 64 + lane];
    bf16x8 r;
#pragma unroll
    for (int j = 0; j < 8; ++j) {
        float x = (float)xi[j];
        r[j] = (bf16)(x + alpha * (acc[j] - x) + beta * (float)xz[j]);
    }
    ((bf16x8*)xout)[(size_t)row * 64 + lane] = r;
}

// ---------- epilogue 1: z = relu(nf*x8 + h); column sums + global sum/sumsq ----------
__global__ void epi1(const bf16* __restrict__ x8, const bf16* __restrict__ h,
                     const float* __restrict__ nf_p, float* __restrict__ z,
                     float* __restrict__ colsum, float* __restrict__ gst) {
    __shared__ float r1[512], r2[512];
    int b = blockIdx.x, j = threadIdx.x;   // 512 threads, 8 rows/block
    float nf = nf_p[0];
    float cp = 0.f, sq = 0.f;
    for (int i = 0; i < 8; ++i) {
        size_t idx = (size_t)(b * 8 + i) * HIDD + j;
        float v = nf * (float)x8[idx] + (float)h[idx];
        v = fmaxf(v, 0.f);
        z[idx] = v;
        cp += v; sq += v * v;
    }
    atomicAdd(&colsum[j], cp);
    r1[j] = cp; r2[j] = sq;
    __syncthreads();
    for (int off = 256; off > 0; off >>= 1) {
        if (j < off) { r1[j] += r1[j + off]; r2[j] += r2[j + off]; }
        __syncthreads();
    }
    if (j == 0) { atomicAdd(&gst[0], r1[0]); atomicAdd(&gst[1], r2[0]); }
}

// ---------- epilogue 2: out = (z - colmean) / global_std(ddof=1), fp32 ----------
__global__ void epi2(const float* __restrict__ z, const float* __restrict__ colsum,
                     const float* __restrict__ gst, float* __restrict__ out) {
    size_t idx = (size_t)blockIdx.x * 256 + threadIdx.x;
    int j = (int)(idx & (HIDD - 1));
    float n = (float)NN * (float)HIDD;
    float gmean = gst[0] / n;
    float var = (gst[1] - n * gmean * gmean) / (n - 1.f);
    float istd = rsqrtf(var);
    float mean = colsum[j] * (1.f / (float)NN);
    out[idx] = (z[idx] - mean) * istd;
}

extern "C" void kernel_launch(void* const* d_in, const int* in_sizes, int n_in,
                              void* d_out, int out_size, void* d_ws, size_t ws_size,
                              hipStream_t stream) {
    const float* knn  = (const float*)d_in[0];
    const float* adj  = (const float*)d_in[1];
    const float* nf   = (const float*)d_in[2];
    const float* w1   = (const float*)d_in[3];
    const float* w2   = (const float*)d_in[4];
    const float* W0   = (const float*)d_in[5];
    const float* b0   = (const float*)d_in[6];
    const float* W1   = (const float*)d_in[7];
    const float* b1   = (const float*)d_in[8];
    const float* ew   = (const float*)d_in[9];
    const float* alph = (const float*)d_in[10];
    const float* beta = (const float*)d_in[11];
    const int*   ei   = (const int*)d_in[12];

    char* w = (char*)d_ws;
    size_t off = 0;
    auto alloc = [&](size_t bytes) -> char* {
        char* p = w + off;
        off += (bytes + 255) & ~(size_t)255;
        return p;
    };
    const size_t SZ_NN  = (size_t)NN * NN * sizeof(bf16);      // 32 MiB
    const size_t SZ_TH  = (size_t)HIDD * NN * sizeof(bf16);    // 4 MiB
    bf16* Bar  = (bf16*)alloc(SZ_NN);                 // adjT
    bf16* Car  = (bf16*)alloc(SZ_NN);                 // w2b -> w1b -> W0b / W1b -> ODE x
    bf16* Adjb = (bf16*)alloc(SZ_NN);                 // adj bf16 (straight)
    bf16* knnT = (bf16*)alloc(SZ_TH);
    bf16* tA   = (bf16*)alloc(SZ_TH);
    bf16* tB   = (bf16*)alloc(SZ_TH);                 // ends as H^T
    float* tf  = (float*)alloc((size_t)32 * 1024 * 1024);  // partials / Rf fp32 / z fp32
    bf16* Hm   = (bf16*)alloc(SZ_TH);                 // H [4096,512]
    bf16* Gb   = (bf16*)alloc((size_t)HIDD * HIDD * sizeof(bf16));
    bf16* M0b  = (bf16*)alloc((size_t)HIDD * HIDD * sizeof(bf16));
    bf16* Qtb  = (bf16*)alloc((size_t)HIDD * HIDD * sizeof(bf16));
    bf16* hb   = (bf16*)alloc((size_t)NN * HIDD * sizeof(bf16));  // h in bf16
    float* inv = (float*)alloc(NN * sizeof(float));
    float* n2  = (float*)alloc(NN * sizeof(float));
    int*  cnt  = (int*)alloc(NN * sizeof(int));
    int*  rs   = (int*)alloc((NN + 1) * sizeof(int));
    int*  cur  = (int*)alloc(NN * sizeof(int));
    int*  ccol = (int*)alloc(NE * sizeof(int));
    float* cw  = (float*)alloc(NE * sizeof(float));
    float* colsum = (float*)alloc(HIDD * sizeof(float));
    float* gst = (float*)alloc(2 * sizeof(float));
    float* bp  = (float*)alloc(HIDD * sizeof(float));
    bf16* tfb = (bf16*)tf;                            // bf16 partial view of tf
    bf16* W1b = (bf16*)((char*)Car + 16 * 1024 * 1024);
    bf16* xA  = (bf16*)Car;                           // 4 MiB (W0b dead by then)
    bf16* xB  = (bf16*)Car + (size_t)NN * HIDD;       // next 4 MiB
    (void)ws_size; (void)n_in; (void)in_sizes; (void)out_size;

    dim3 tb(32, 8);
    const int nTH = HIDD * NN;      // 2M elems
    const int nHH = HIDD * HIDD;    // 256K elems

    // ---- prep ----
    transpose_pad_f32<<<dim3(16, 128), tb, 0, stream>>>(knn, knnT, NN, 500, HIDD);
    cvt_f32_bf16<<<(NN * NN) / 1024, 256, 0, stream>>>(w2, Car, NN * NN);
    transpose_dual_f32<<<dim3(128, 128), tb, 0, stream>>>(adj, Bar, Adjb, NN);

    // ---- chain (transposed): t1^T=knn^T w2^T ; t2^T=t1^T adj ; t3^T=t2^T w1^T ; H^T=t3^T adj^T
    // NT with B = {w2, adjT, w1, adj}; split-K=8 bf16 partials in tf, deterministic reduce.
    gemm_nt<2, false, false><<<dim3(32, 4, 8), 256, 0, stream>>>(knnT, Car, tfb, nullptr, nullptr, HIDD, NN, NN);
    reduce_bf16_slices<<<nTH / 2048, 256, 0, stream>>>(tfb, tA, nTH, 8);
    gemm_nt<2, false, false><<<dim3(32, 4, 8), 256, 0, stream>>>(tA, Bar, tfb, nullptr, nullptr, HIDD, NN, NN);
    reduce_bf16_slices<<<nTH / 2048, 256, 0, stream>>>(tfb, tB, nTH, 8);
    cvt_f32_bf16<<<(NN * NN) / 1024, 256, 0, stream>>>(w1, Car, NN * NN);
    gemm_nt<2, false, false><<<dim3(32, 4, 8), 256, 0, stream>>>(tB, Car, tfb, nullptr, nullptr, HIDD, NN, NN);
    reduce_bf16_slices<<<nTH / 2048, 256, 0, stream>>>(tfb, tA, nTH, 8);
    gemm_nt<2, false, false><<<dim3(32, 4, 8), 256, 0, stream>>>(tA, Adjb, tfb, nullptr, nullptr, HIDD, NN, NN);
    reduce_bf16_slices<<<nTH / 2048, 256, 0, stream>>>(tfb, tB, nTH, 8);   // tB = H^T

    // ---- H [4096,512] ----
    transpose_bf16<<<dim3(128, 16), tb, 0, stream>>>(tB, Hm, HIDD, NN);

    // ---- G = H^T H  [512,512], split-K=32 ----
    gemm_nt<2, false, false><<<dim3(4, 4, 32), 256, 0, stream>>>(tB, tB, tfb, nullptr, nullptr, HIDD, HIDD, NN);
    reduce_bf16_slices<<<nHH / 2048, 256, 0, stream>>>(tfb, Gb, nHH, 32);

    // ---- R^T = G H^T  [512,4096] fp32, split-K=2 (K=512) ----
    gemm_nt<0, false, false><<<dim3(32, 4, 2), 256, 0, stream>>>(Gb, Hm, tf, nullptr, nullptr, HIDD, NN, HIDD);
    // ---- norms: inv[i] = 1/max(sqrt(sum_a (R^T slices)[a,i]*H^T[a,i]), 1e-12) ----
    hipMemsetAsync(n2, 0, NN * sizeof(float), stream);
    colnorm_part<<<dim3(32, 8), 128, 0, stream>>>(tB, tf, n2);
    colnorm_fin<<<NN / 256, 256, 0, stream>>>(n2, inv);

    // ---- M0 = H^T W0^T  [512,512], split-K=32 ----
    cvt_f32_bf16<<<(HIDD * NN) / 1024, 256, 0, stream>>>(W0, Car, HIDD * NN);
    gemm_nt<2, false, false><<<dim3(4, 4, 32), 256, 0, stream>>>(tB, Car, tfb, nullptr, nullptr, HIDD, HIDD, NN);
    reduce_bf16_slices<<<nHH / 2048, 256, 0, stream>>>(tfb, M0b, nHH, 32);

    // ---- Q^T = W1 M0^T  [512,512], split-K=8 (K=512) ----
    cvt_f32_bf16<<<(HIDD * HIDD) / 1024, 256, 0, stream>>>(W1, W1b, HIDD * HIDD);
    gemm_nt<2, false, false><<<dim3(4, 4, 8), 256, 0, stream>>>(W1b, M0b, tfb, nullptr, nullptr, HIDD, HIDD, HIDD);
    reduce_bf16_slices<<<nHH / 2048, 256, 0, stream>>>(tfb, Qtb, nHH, 8);

    // ---- b' = W1 b0 + b1 ----
    bias_fuse<<<128, 256, 0, stream>>>(W1, b0, b1, bp);

    // ---- h = diag(inv) H Q + b'  [4096,512] bf16, split-K=2 (K=512) ----
    gemm_nt<2, false, false><<<dim3(4, 32, 2), 256, 0, stream>>>(Hm, Qtb, tfb, nullptr, nullptr, NN, HIDD, HIDD);
    reduce2_scale_bias<<<(NN * HIDD) / 2048, 256, 0, stream>>>(tfb, hb, inv, bp);

    // ---- CSR build ----
    hipMemsetAsync(cnt, 0, NN * sizeof(int), stream);
    csr_count<<<NE / 256, 256, 0, stream>>>(ei, cnt, NE);
    scan_4096<<<1, 1024, 0, stream>>>(cnt, rs);
    hipMemcpyAsync(cur, rs, NN * sizeof(int), hipMemcpyDeviceToDevice, stream);
    csr_scatter<<<NE / 256, 256, 0, stream>>>(ei, ew, cur, ccol, cw, NE);

    // ---- 8 Euler steps (bf16 state): hb -> xA -> xB -> ... -> final in xB ----
    const bf16* xi = hb;
    bf16* xo = xA;
    for (int s = 0; s < 8; ++s) {
        ode_step_bf16<<<NN / 4, 256, 0, stream>>>(xi, hb, xo, rs, ccol, cw, alph, beta);
        xi = xo;
        xo = (s % 2 == 0) ? xB : xA;
    }

    // ---- epilogue ----
    hipMemsetAsync(colsum, 0, HIDD * sizeof(float), stream);
    hipMemsetAsync(gst, 0, 2 * sizeof(float), stream);
    epi1<<<NN / 8, 512, 0, stream>>>(xB, hb, nf, tf, colsum, gst);
    epi2<<<(NN * HIDD) / 256, 256, 0, stream>>>(tf, colsum, gst, (float*)d_out);
}

// Round 2
// 648.823 us; speedup vs baseline: 1.0698x; 1.0698x over previous
//
#include <hip/hip_runtime.h>
#include <stdint.h>
#include <stddef.h>

typedef __bf16 bf16;
typedef __attribute__((ext_vector_type(8))) __bf16 bf16x8;
typedef __attribute__((ext_vector_type(4))) __bf16 bf16x4;
typedef __attribute__((ext_vector_type(4))) float f32x4;

#define NN 4096
#define HIDD 512
#define NE 65536

// ---------- async global->LDS, 16B per lane, wave-uniform LDS base ----------
__device__ inline void gll16(const void* g, void* l) {
    __builtin_amdgcn_global_load_lds(
        (const __attribute__((address_space(1))) void*)g,
        (__attribute__((address_space(3))) void*)l, 16, 0, 0);
}

// ---------- fp32 -> bf16 elementwise convert (n multiple of 1024) ----------
__global__ void cvt_f32_bf16(const float* __restrict__ in, bf16* __restrict__ out, int n) {
    int i = (blockIdx.x * 256 + threadIdx.x) * 4;
    if (i >= n) return;
    float4 v = *reinterpret_cast<const float4*>(in + i);
    bf16x4 o;
    o[0] = (bf16)v.x; o[1] = (bf16)v.y; o[2] = (bf16)v.z; o[3] = (bf16)v.w;
    *reinterpret_cast<bf16x4*>(out + i) = o;
}

// ---------- sum S bf16 slices of n elems -> bf16 (n multiple of 2048) ----------
__global__ void reduce_bf16_slices(const bf16* __restrict__ in, bf16* __restrict__ out,
                                   int n, int S) {
    int i = (blockIdx.x * 256 + threadIdx.x) * 8;
    if (i >= n) return;
    float acc[8] = {};
    for (int k = 0; k < S; ++k) {
        bf16x8 v = *reinterpret_cast<const bf16x8*>(in + (size_t)k * n + i);
#pragma unroll
        for (int j = 0; j < 8; ++j) acc[j] += (float)v[j];
    }
    bf16x8 o;
#pragma unroll
    for (int j = 0; j < 8; ++j) o[j] = (bf16)acc[j];
    *reinterpret_cast<bf16x8*>(out + i) = o;
}

// ---------- fp32 transpose -> bf16 with column zero-padding: out[c][r] = in[r][c] ----------
__global__ void transpose_pad_f32(const float* __restrict__ in, bf16* __restrict__ out,
                                  int R, int C, int Cpad) {
    __shared__ bf16 tile[32][33];
    int c0 = blockIdx.x * 32, r0 = blockIdx.y * 32;
    int tx = threadIdx.x, ty = threadIdx.y;
    for (int i = ty; i < 32; i += 8) {
        int r = r0 + i, c = c0 + tx;
        bf16 v = (bf16)0.f;
        if (r < R && c < C) v = (bf16)in[(size_t)r * C + c];
        tile[i][tx] = v;
    }
    __syncthreads();
    for (int i = ty; i < 32; i += 8) {
        int oc = c0 + i, orow = r0 + tx;
        if (oc < Cpad && orow < R) out[(size_t)oc * R + orow] = tile[tx][i];
    }
}

// ---------- fp32 square matrix: one read, write bf16(in^T) and bf16(in), vectorized ----------
// 64x64 tile, 256 threads. float4 loads, bf16x4 row-major stores, bf16x8 transposed stores.
__global__ void transpose_dual_f32(const float* __restrict__ in, bf16* __restrict__ outT,
                                   bf16* __restrict__ outD, int Nn) {
    __shared__ bf16 tile[64][68];
    int r0 = blockIdx.y * 64, c0 = blockIdx.x * 64;
    int t = threadIdx.x;
    int tx = t & 15;          // col group (4 floats)
    int ty = t >> 4;          // row base, 16 rows per step
#pragma unroll
    for (int i = 0; i < 4; ++i) {
        int r = ty + i * 16;
        float4 v = *reinterpret_cast<const float4*>(in + (size_t)(r0 + r) * Nn + c0 + tx * 4);
        bf16x4 o;
        o[0] = (bf16)v.x; o[1] = (bf16)v.y; o[2] = (bf16)v.z; o[3] = (bf16)v.w;
        *reinterpret_cast<bf16x4*>(&tile[r][tx * 4]) = o;
        *reinterpret_cast<bf16x4*>(outD + (size_t)(r0 + r) * Nn + c0 + tx * 4) = o;
    }
    __syncthreads();
    int c = t >> 2;               // local col -> output row
    int rs = (t & 3) * 16;        // 16 source rows per thread
#pragma unroll
    for (int j = 0; j < 2; ++j) {
        int r = rs + j * 8;
        bf16x8 o;
#pragma unroll
        for (int e = 0; e < 8; ++e) o[e] = tile[r + e][c];
        *reinterpret_cast<bf16x8*>(outT + (size_t)(c0 + c) * Nn + r0 + r) = o;
    }
}

// ---------- bf16 transpose: out[c][r] = in[r][c], dims multiple of 32 ----------
__global__ void transpose_bf16(const bf16* __restrict__ in, bf16* __restrict__ out,
                               int R, int C) {
    __shared__ bf16 tile[32][33];
    int c0 = blockIdx.x * 32, r0 = blockIdx.y * 32;
    int tx = threadIdx.x, ty = threadIdx.y;
    for (int i = ty; i < 32; i += 8)
        tile[i][tx] = in[(size_t)(r0 + i) * C + c0 + tx];
    __syncthreads();
    for (int i = ty; i < 32; i += 8)
        out[(size_t)(c0 + i) * R + r0 + tx] = tile[tx][i];
}

// ---------- NT GEMM: C[M,N] = A[M,K] * B[N,K]^T ----------
// m97 fragment layout + depth-2 software pipeline:
//   3 LDS buffers, tile t+2 issued while computing tile t, counted vmcnt(4),
//   raw s_barrier (no vmcnt(0) drain in steady state -- T3/T4 pattern).
// OMODE: 0 = fp32 out at Cp + z*M*N; 1 = bf16 out; 2 = bf16 partial at Cp + z*M*N
template<int OMODE, bool HAS_BIAS, bool ROW_SCALE>
__global__ __launch_bounds__(256)
void gemm_nt(const bf16* __restrict__ A, const bf16* __restrict__ B,
             void* __restrict__ Cp, const float* __restrict__ bias,
             const float* __restrict__ rowscale, int M, int N, int K) {
    __shared__ __align__(16) bf16 As[3][128 * 32];
    __shared__ __align__(16) bf16 Bs[3][128 * 32];
    const int tid  = threadIdx.x;
    const int wave = tid >> 6;
    const int lane = tid & 63;
    const int m0 = blockIdx.y * 128, n0 = blockIdx.x * 128;
    const int lrow = lane >> 2;
    const int lcol = (lane & 3) * 8;
    const int c0 = wave * 2;
    const size_t arow0 = (size_t)(m0 + c0 * 16 + lrow) * K + lcol;
    const size_t arow1 = (size_t)(m0 + (c0 + 1) * 16 + lrow) * K + lcol;
    const size_t brow0 = (size_t)(n0 + c0 * 16 + lrow) * K + lcol;
    const size_t brow1 = (size_t)(n0 + (c0 + 1) * 16 + lrow) * K + lcol;

    f32x4 acc[4][4] = {};

    const int wm = (wave >> 1) * 64;
    const int wn = (wave & 1) * 64;
    const int fm = wm + (lane & 15);
    const int fn = wn + (lane & 15);
    const int fk = (lane >> 4) * 8;

    const int kper = K / gridDim.z;
    const int kz0 = blockIdx.z * kper;
    const int nt = kper >> 5;

    auto stage = [&](int t, int buf) {
        const int k0 = kz0 + (t << 5);
        gll16(A + arow0 + k0, &As[buf][c0 * 512]);
        gll16(A + arow1 + k0, &As[buf][(c0 + 1) * 512]);
        gll16(B + brow0 + k0, &Bs[buf][c0 * 512]);
        gll16(B + brow1 + k0, &Bs[buf][(c0 + 1) * 512]);
    };

    // prologue: tiles 0 and 1 in flight (8 outstanding vmem ops per wave)
    stage(0, 0);
    if (nt > 1) stage(1, 1);

    int cur = 0;
    for (int t = 0; t < nt; ++t) {
        // wait for tile t only (tile t+1's 4 loads stay in flight)
        if (t + 1 < nt) asm volatile("s_waitcnt vmcnt(4)" ::: "memory");
        else            asm volatile("s_waitcnt vmcnt(0)" ::: "memory");
        __builtin_amdgcn_s_barrier();
        // issue tile t+2 into the buffer freed at the barrier above
        if (t + 2 < nt) {
            int nb = cur + 2; if (nb >= 3) nb -= 3;
            stage(t + 2, nb);
        }
        bf16x8 af[4], bg[4];
#pragma unroll
        for (int i = 0; i < 4; ++i)
            af[i] = *reinterpret_cast<const bf16x8*>(&As[cur][(fm + i * 16) * 32 + fk]);
#pragma unroll
        for (int j = 0; j < 4; ++j)
            bg[j] = *reinterpret_cast<const bf16x8*>(&Bs[cur][(fn + j * 16) * 32 + fk]);
#pragma unroll
        for (int i = 0; i < 4; ++i)
#pragma unroll
            for (int j = 0; j < 4; ++j)
                acc[i][j] = __builtin_amdgcn_mfma_f32_16x16x32_bf16(af[i], bg[j], acc[i][j], 0, 0, 0);
        cur = (cur + 1 == 3) ? 0 : cur + 1;
    }

    const int rbase = m0 + wm + (lane >> 4) * 4;
    const int cbase = n0 + wn + (lane & 15);
    float* outf = (float*)Cp + (size_t)blockIdx.z * M * N;
    bf16*  outb = (bf16*)Cp;
    bf16*  outp = (bf16*)Cp + (size_t)blockIdx.z * M * N;
#pragma unroll
    for (int i = 0; i < 4; ++i) {
#pragma unroll
        for (int j = 0; j < 4; ++j) {
            int col = cbase + j * 16;
            float bv = 0.f;
            if (HAS_BIAS) bv = bias[col];
#pragma unroll
            for (int r = 0; r < 4; ++r) {
                int row = rbase + i * 16 + r;
                float v = acc[i][j][r];
                if (ROW_SCALE) v *= rowscale[row];
                v += bv;
                if (OMODE == 0)      outf[(size_t)row * N + col] = v;
                else if (OMODE == 1) outb[(size_t)row * N + col] = (bf16)v;
                else                 outp[(size_t)row * N + col] = (bf16)v;
            }
        }
    }
}

// ---------- colnorm partials: n2[i] += sum_{a in chunk} (Rf0+Rf1)[a,i]*Ht[a,i] ----------
__global__ void colnorm_part(const bf16* __restrict__ Ht, const float* __restrict__ Rf,
                             float* __restrict__ n2) {
    int i = blockIdx.x * 128 + threadIdx.x;   // 32 x-blocks cover 4096 cols
    int a0 = blockIdx.y * 64;                 // 8 y-blocks cover 512 rows
    const float* Rf2 = Rf + (size_t)HIDD * NN;
    float s = 0.f;
    for (int a = a0; a < a0 + 64; ++a) {
        size_t idx = (size_t)a * NN + i;
        s += (Rf[idx] + Rf2[idx]) * (float)Ht[idx];
    }
    atomicAdd(&n2[i], s);
}

__global__ void colnorm_fin(const float* __restrict__ n2, float* __restrict__ inv) {
    int i = blockIdx.x * 256 + threadIdx.x;
    inv[i] = 1.f / fmaxf(sqrtf(n2[i]), 1e-12f);
}

// ---------- b' = W1 @ b0 + b1  (one wave per row) ----------
__global__ void bias_fuse(const float* __restrict__ W1, const float* __restrict__ b0,
                          const float* __restrict__ b1, float* __restrict__ bp) {
    int row = blockIdx.x * 4 + (threadIdx.x >> 6);
    int lane = threadIdx.x & 63;
    const float4* wr = (const float4*)(W1 + (size_t)row * HIDD);
    const float4* bz = (const float4*)b0;
    float s = 0.f;
#pragma unroll
    for (int j = 0; j < 2; ++j) {
        float4 a = wr[lane * 2 + j], b = bz[lane * 2 + j];
        s += a.x * b.x + a.y * b.y + a.z * b.z + a.w * b.w;
    }
    for (int off = 32; off; off >>= 1) s += __shfl_down(s, off);
    if (lane == 0) bp[row] = b1[row] + s;
}

// ---------- reduce 2 bf16 slices + rowscale + colbias -> bf16 (h epilogue) ----------
__global__ void reduce2_scale_bias(const bf16* __restrict__ p, bf16* __restrict__ out,
                                   const float* __restrict__ inv, const float* __restrict__ bp) {
    int i = (blockIdx.x * 256 + threadIdx.x) * 8;
    const int n = NN * HIDD;
    bf16x8 a = *reinterpret_cast<const bf16x8*>(p + i);
    bf16x8 b = *reinterpret_cast<const bf16x8*>(p + n + i);
    int row = i >> 9;           // HIDD = 512
    int col = i & (HIDD - 1);
    float sc = inv[row];
    bf16x8 o;
#pragma unroll
    for (int j = 0; j < 8; ++j)
        o[j] = (bf16)(((float)a[j] + (float)b[j]) * sc + bp[col + j]);
    *reinterpret_cast<bf16x8*>(out + i) = o;
}

// ---------- CSR build ----------
__global__ void csr_count(const int* __restrict__ ei, int* __restrict__ cnt, int E) {
    int e = blockIdx.x * 256 + threadIdx.x;
    if (e < E) atomicAdd(&cnt[ei[e]], 1);
}

__global__ void scan_4096(const int* __restrict__ cnt, int* __restrict__ rs) {
    __shared__ int s[1024];
    int t = threadIdx.x;
    int b = t * 4;
    int a0 = cnt[b], a1 = cnt[b + 1], a2 = cnt[b + 2], a3 = cnt[b + 3];
    int tot = a0 + a1 + a2 + a3;
    s[t] = tot;
    __syncthreads();
    for (int off = 1; off < 1024; off <<= 1) {
        int v = (t >= off) ? s[t - off] : 0;
        __syncthreads();
        s[t] += v;
        __syncthreads();
    }
    int excl = s[t] - tot;
    rs[b] = excl; rs[b + 1] = excl + a0; rs[b + 2] = excl + a0 + a1; rs[b + 3] = excl + a0 + a1 + a2;
    if (t == 1023) rs[4096] = s[1023];
}

__global__ void csr_scatter(const int* __restrict__ ei, const float* __restrict__ ew,
                            int* __restrict__ cur, int* __restrict__ ccol,
                            float* __restrict__ cw, int E) {
    int e = blockIdx.x * 256 + threadIdx.x;
    if (e < E) {
        int r = ei[e];
        int p = atomicAdd(&cur[r], 1);
        ccol[p] = ei[E + e];
        cw[p] = ew[e];
    }
}

// ---------- one Euler diffusion step in bf16: x' = x + alpha*(Ax - x) + beta*x0 ----------
__global__ void ode_step_bf16(const bf16* __restrict__ xin, const bf16* __restrict__ x0,
                              bf16* __restrict__ xout, const int* __restrict__ rs,
                              const int* __restrict__ ccol, const float* __restrict__ cw,
                              const float* __restrict__ alpha_p, const float* __restrict__ beta_p) {
    int row = blockIdx.x * 4 + (threadIdx.x >> 6);
    int lane = threadIdx.x & 63;
    float alpha = 1.f / (1.f + expf(-alpha_p[0]));
    float beta = beta_p[0];
    const bf16x8* xin8 = (const bf16x8*)xin;
    float acc[8] = {};
    int p0 = rs[row], p1 = rs[row + 1];
    for (int p = p0; p < p1; ++p) {
        int c = ccol[p]; float w = cw[p];
        bf16x8 v = xin8[(size_t)c * 64 + lane];
#pragma unroll
        for (int j = 0; j < 8; ++j) acc[j] += w * (float)v[j];
    }
    bf16x8 xi = xin8[(size_t)row * 64 + lane];
    bf16x8 xz = ((const bf16x8*)x0)[(size_t)row * 64 + lane];
    bf16x8 r;
#pragma unroll
    for (int j = 0; j < 8; ++j) {
        float x = (float)xi[j];
        r[j] = (bf16)(x + alpha * (acc[j] - x) + beta * (float)xz[j]);
    }
    ((bf16x8*)xout)[(size_t)row * 64 + lane] = r;
}

// ---------- epilogue 1: z = relu(nf*x8 + h); column sums + global sum/sumsq ----------
__global__ void epi1(const bf16* __restrict__ x8, const bf16* __restrict__ h,
                     const float* __restrict__ nf_p, float* __restrict__ z,
                     float* __restrict__ colsum, float* __restrict__ gst) {
    __shared__ float r1[512], r2[512];
    int b = blockIdx.x, j = threadIdx.x;   // 512 threads, 8 rows/block
    float nf = nf_p[0];
    float cp = 0.f, sq = 0.f;
    for (int i = 0; i < 8; ++i) {
        size_t idx = (size_t)(b * 8 + i) * HIDD + j;
        float v = nf * (float)x8[idx] + (float)h[idx];
        v = fmaxf(v, 0.f);
        z[idx] = v;
        cp += v; sq += v * v;
    }
    atomicAdd(&colsum[j], cp);
    r1[j] = cp; r2[j] = sq;
    __syncthreads();
    for (int off = 256; off > 0; off >>= 1) {
        if (j < off) { r1[j] += r1[j + off]; r2[j] += r2[j + off]; }
        __syncthreads();
    }
    if (j == 0) { atomicAdd(&gst[0], r1[0]); atomicAdd(&gst[1], r2[0]); }
}

// ---------- epilogue 2: out = (z - colmean) / global_std(ddof=1), fp32 ----------
__global__ void epi2(const float* __restrict__ z, const float* __restrict__ colsum,
                     const float* __restrict__ gst, float* __restrict__ out) {
    size_t idx = (size_t)blockIdx.x * 256 + threadIdx.x;
    int j = (int)(idx & (HIDD - 1));
    float n = (float)NN * (float)HIDD;
    float gmean = gst[0] / n;
    float var = (gst[1] - n * gmean * gmean) / (n - 1.f);
    float istd = rsqrtf(var);
    float mean = colsum[j] * (1.f / (float)NN);
    out[idx] = (z[idx] - mean) * istd;
}

extern "C" void kernel_launch(void* const* d_in, const int* in_sizes, int n_in,
                              void* d_out, int out_size, void* d_ws, size_t ws_size,
                              hipStream_t stream) {
    const float* knn  = (const float*)d_in[0];
    const float* adj  = (const float*)d_in[1];
    const float* nf   = (const float*)d_in[2];
    const float* w1   = (const float*)d_in[3];
    const float* w2   = (const float*)d_in[4];
    const float* W0   = (const float*)d_in[5];
    const float* b0   = (const float*)d_in[6];
    const float* W1   = (const float*)d_in[7];
    const float* b1   = (const float*)d_in[8];
    const float* ew   = (const float*)d_in[9];
    const float* alph = (const float*)d_in[10];
    const float* beta = (const float*)d_in[11];
    const int*   ei   = (const int*)d_in[12];

    char* w = (char*)d_ws;
    size_t off = 0;
    auto alloc = [&](size_t bytes) -> char* {
        char* p = w + off;
        off += (bytes + 255) & ~(size_t)255;
        return p;
    };
    const size_t SZ_NN  = (size_t)NN * NN * sizeof(bf16);      // 32 MiB
    const size_t SZ_TH  = (size_t)HIDD * NN * sizeof(bf16);    // 4 MiB
    bf16* Bar  = (bf16*)alloc(SZ_NN);                 // adjT
    bf16* Car  = (bf16*)alloc(SZ_NN);                 // w2b -> w1b -> W0b / W1b -> ODE x
    bf16* Adjb = (bf16*)alloc(SZ_NN);                 // adj bf16 (straight)
    bf16* knnT = (bf16*)alloc(SZ_TH);
    bf16* tA   = (bf16*)alloc(SZ_TH);
    bf16* tB   = (bf16*)alloc(SZ_TH);                 // ends as H^T
    float* tf  = (float*)alloc((size_t)32 * 1024 * 1024);  // partials / Rf fp32 / z fp32
    bf16* Hm   = (bf16*)alloc(SZ_TH);                 // H [4096,512]
    bf16* Gb   = (bf16*)alloc((size_t)HIDD * HIDD * sizeof(bf16));
    bf16* M0b  = (bf16*)alloc((size_t)HIDD * HIDD * sizeof(bf16));
    bf16* Qtb  = (bf16*)alloc((size_t)HIDD * HIDD * sizeof(bf16));
    bf16* hb   = (bf16*)alloc((size_t)NN * HIDD * sizeof(bf16));  // h in bf16
    float* inv = (float*)alloc(NN * sizeof(float));
    float* n2  = (float*)alloc(NN * sizeof(float));
    int*  cnt  = (int*)alloc(NN * sizeof(int));
    int*  rs   = (int*)alloc((NN + 1) * sizeof(int));
    int*  cur  = (int*)alloc(NN * sizeof(int));
    int*  ccol = (int*)alloc(NE * sizeof(int));
    float* cw  = (float*)alloc(NE * sizeof(float));
    float* colsum = (float*)alloc(HIDD * sizeof(float));
    float* gst = (float*)alloc(2 * sizeof(float));
    float* bp  = (float*)alloc(HIDD * sizeof(float));
    bf16* tfb = (bf16*)tf;                            // bf16 partial view of tf
    bf16* W1b = (bf16*)((char*)Car + 16 * 1024 * 1024);
    bf16* xA  = (bf16*)Car;                           // 4 MiB (W0b dead by then)
    bf16* xB  = (bf16*)Car + (size_t)NN * HIDD;       // next 4 MiB
    (void)ws_size; (void)n_in; (void)in_sizes; (void)out_size;

    dim3 tb(32, 8);
    const int nTH = HIDD * NN;      // 2M elems
    const int nHH = HIDD * HIDD;    // 256K elems

    // ---- prep ----
    transpose_pad_f32<<<dim3(16, 128), tb, 0, stream>>>(knn, knnT, NN, 500, HIDD);
    cvt_f32_bf16<<<(NN * NN) / 1024, 256, 0, stream>>>(w2, Car, NN * NN);
    transpose_dual_f32<<<dim3(64, 64), 256, 0, stream>>>(adj, Bar, Adjb, NN);

    // ---- chain (transposed): t1^T=knn^T w2^T ; t2^T=t1^T adj ; t3^T=t2^T w1^T ; H^T=t3^T adj^T
    // NT with B = {w2, adjT, w1, adj}; split-K=4 bf16 partials in tf, deterministic reduce.
    gemm_nt<2, false, false><<<dim3(32, 4, 4), 256, 0, stream>>>(knnT, Car, tfb, nullptr, nullptr, HIDD, NN, NN);
    reduce_bf16_slices<<<nTH / 2048, 256, 0, stream>>>(tfb, tA, nTH, 4);
    gemm_nt<2, false, false><<<dim3(32, 4, 4), 256, 0, stream>>>(tA, Bar, tfb, nullptr, nullptr, HIDD, NN, NN);
    reduce_bf16_slices<<<nTH / 2048, 256, 0, stream>>>(tfb, tB, nTH, 4);
    cvt_f32_bf16<<<(NN * NN) / 1024, 256, 0, stream>>>(w1, Car, NN * NN);
    gemm_nt<2, false, false><<<dim3(32, 4, 4), 256, 0, stream>>>(tB, Car, tfb, nullptr, nullptr, HIDD, NN, NN);
    reduce_bf16_slices<<<nTH / 2048, 256, 0, stream>>>(tfb, tA, nTH, 4);
    gemm_nt<2, false, false><<<dim3(32, 4, 4), 256, 0, stream>>>(tA, Adjb, tfb, nullptr, nullptr, HIDD, NN, NN);
    reduce_bf16_slices<<<nTH / 2048, 256, 0, stream>>>(tfb, tB, nTH, 4);   // tB = H^T

    // ---- H [4096,512] ----
    transpose_bf16<<<dim3(128, 16), tb, 0, stream>>>(tB, Hm, HIDD, NN);

    // ---- G = H^T H  [512,512], split-K=32 ----
    gemm_nt<2, false, false><<<dim3(4, 4, 32), 256, 0, stream>>>(tB, tB, tfb, nullptr, nullptr, HIDD, HIDD, NN);
    reduce_bf16_slices<<<nHH / 2048, 256, 0, stream>>>(tfb, Gb, nHH, 32);

    // ---- R^T = G H^T  [512,4096] fp32, split-K=2 (K=512) ----
    gemm_nt<0, false, false><<<dim3(32, 4, 2), 256, 0, stream>>>(Gb, Hm, tf, nullptr, nullptr, HIDD, NN, HIDD);
    // ---- norms: inv[i] = 1/max(sqrt(sum_a (R^T slices)[a,i]*H^T[a,i]), 1e-12) ----
    hipMemsetAsync(n2, 0, NN * sizeof(float), stream);
    colnorm_part<<<dim3(32, 8), 128, 0, stream>>>(tB, tf, n2);
    colnorm_fin<<<NN / 256, 256, 0, stream>>>(n2, inv);

    // ---- M0 = H^T W0^T  [512,512], split-K=32 ----
    cvt_f32_bf16<<<(HIDD * NN) / 1024, 256, 0, stream>>>(W0, Car, HIDD * NN);
    gemm_nt<2, false, false><<<dim3(4, 4, 32), 256, 0, stream>>>(tB, Car, tfb, nullptr, nullptr, HIDD, HIDD, NN);
    reduce_bf16_slices<<<nHH / 2048, 256, 0, stream>>>(tfb, M0b, nHH, 32);

    // ---- Q^T = W1 M0^T  [512,512], split-K=8 (K=512) ----
    cvt_f32_bf16<<<(HIDD * HIDD) / 1024, 256, 0, stream>>>(W1, W1b, HIDD * HIDD);
    gemm_nt<2, false, false><<<dim3(4, 4, 8), 256, 0, stream>>>(W1b, M0b, tfb, nullptr, nullptr, HIDD, HIDD, HIDD);
    reduce_bf16_slices<<<nHH / 2048, 256, 0, stream>>>(tfb, Qtb, nHH, 8);

    // ---- b' = W1 b0 + b1 ----
    bias_fuse<<<128, 256, 0, stream>>>(W1, b0, b1, bp);

    // ---- h = diag(inv) H Q + b'  [4096,512] bf16, split-K=2 (K=512) ----
    gemm_nt<2, false, false><<<dim3(4, 32, 2), 256, 0, stream>>>(Hm, Qtb, tfb, nullptr, nullptr, NN, HIDD, HIDD);
    reduce2_scale_bias<<<(NN * HIDD) / 2048, 256, 0, stream>>>(tfb, hb, inv, bp);

    // ---- CSR build ----
    hipMemsetAsync(cnt, 0, NN * sizeof(int), stream);
    csr_count<<<NE / 256, 256, 0, stream>>>(ei, cnt, NE);
    scan_4096<<<1, 1024, 0, stream>>>(cnt, rs);
    hipMemcpyAsync(cur, rs, NN * sizeof(int), hipMemcpyDeviceToDevice, stream);
    csr_scatter<<<NE / 256, 256, 0, stream>>>(ei, ew, cur, ccol, cw, NE);

    // ---- 8 Euler steps (bf16 state): hb -> xA -> xB -> ... -> final in xB ----
    const bf16* xi = hb;
    bf16* xo = xA;
    for (int s = 0; s < 8; ++s) {
        ode_step_bf16<<<NN / 4, 256, 0, stream>>>(xi, hb, xo, rs, ccol, cw, alph, beta);
        xi = xo;
        xo = (s % 2 == 0) ? xB : xA;
    }

    // ---- epilogue ----
    hipMemsetAsync(colsum, 0, HIDD * sizeof(float), stream);
    hipMemsetAsync(gst, 0, 2 * sizeof(float), stream);
    epi1<<<NN / 8, 512, 0, stream>>>(xB, hb, nf, tf, colsum, gst);
    epi2<<<(NN * HIDD) / 256, 256, 0, stream>>>(tf, colsum, gst, (float*)d_out);
}

// Round 3
// 645.177 us; speedup vs baseline: 1.0758x; 1.0057x over previous
//
#include <hip/hip_runtime.h>
#include <stdint.h>
#include <stddef.h>

typedef __bf16 bf16;
typedef __attribute__((ext_vector_type(8))) __bf16 bf16x8;
typedef __attribute__((ext_vector_type(4))) __bf16 bf16x4;
typedef __attribute__((ext_vector_type(4))) float f32x4;

#define NN 4096
#define HIDD 512
#define NE 65536

// ---------- async global->LDS, 16B per lane, wave-uniform LDS base ----------
__device__ inline void gll16(const void* g, void* l) {
    __builtin_amdgcn_global_load_lds(
        (const __attribute__((address_space(1))) void*)g,
        (__attribute__((address_space(3))) void*)l, 16, 0, 0);
}

// ---------- fp32 -> bf16 elementwise convert (n multiple of 1024) ----------
__global__ void cvt_f32_bf16(const float* __restrict__ in, bf16* __restrict__ out, int n) {
    int i = (blockIdx.x * 256 + threadIdx.x) * 4;
    if (i >= n) return;
    float4 v = *reinterpret_cast<const float4*>(in + i);
    bf16x4 o;
    o[0] = (bf16)v.x; o[1] = (bf16)v.y; o[2] = (bf16)v.z; o[3] = (bf16)v.w;
    *reinterpret_cast<bf16x4*>(out + i) = o;
}

// ---------- sum S bf16 slices of n elems -> bf16 (n multiple of 2048) ----------
__global__ void reduce_bf16_slices(const bf16* __restrict__ in, bf16* __restrict__ out,
                                   int n, int S) {
    int i = (blockIdx.x * 256 + threadIdx.x) * 8;
    if (i >= n) return;
    float acc[8] = {};
    for (int k = 0; k < S; ++k) {
        bf16x8 v = *reinterpret_cast<const bf16x8*>(in + (size_t)k * n + i);
#pragma unroll
        for (int j = 0; j < 8; ++j) acc[j] += (float)v[j];
    }
    bf16x8 o;
#pragma unroll
    for (int j = 0; j < 8; ++j) o[j] = (bf16)acc[j];
    *reinterpret_cast<bf16x8*>(out + i) = o;
}

// ---------- fp32 transpose -> bf16 with column zero-padding: out[c][r] = in[r][c] ----------
__global__ void transpose_pad_f32(const float* __restrict__ in, bf16* __restrict__ out,
                                  int R, int C, int Cpad) {
    __shared__ bf16 tile[32][33];
    int c0 = blockIdx.x * 32, r0 = blockIdx.y * 32;
    int tx = threadIdx.x, ty = threadIdx.y;
    for (int i = ty; i < 32; i += 8) {
        int r = r0 + i, c = c0 + tx;
        bf16 v = (bf16)0.f;
        if (r < R && c < C) v = (bf16)in[(size_t)r * C + c];
        tile[i][tx] = v;
    }
    __syncthreads();
    for (int i = ty; i < 32; i += 8) {
        int oc = c0 + i, orow = r0 + tx;
        if (oc < Cpad && orow < R) out[(size_t)oc * R + orow] = tile[tx][i];
    }
}

// ---------- fp32 square matrix: one read, write bf16(in^T) and bf16(in), 16B stores ----------
// 64x64 tile, 256 threads. Phase 1: each thread 2 rows x 8 cols (2x float4 -> bf16x8),
// stores outD + LDS. Phase 2: each thread gathers 2x 8 rows of one column -> bf16x8 outT.
__global__ void transpose_dual_f32(const float* __restrict__ in, bf16* __restrict__ outT,
                                   bf16* __restrict__ outD, int Nn) {
    __shared__ bf16 tile[64][66];
    int r0 = blockIdx.y * 64, c0 = blockIdx.x * 64;
    int t = threadIdx.x;
    int tx = t & 7;           // 8 col groups of 8
    int ty = t >> 3;          // 32 rows per pass
#pragma unroll
    for (int i = 0; i < 2; ++i) {
        int r = ty + i * 32;
        const float* src = in + (size_t)(r0 + r) * Nn + c0 + tx * 8;
        float4 v0 = *reinterpret_cast<const float4*>(src);
        float4 v1 = *reinterpret_cast<const float4*>(src + 4);
        bf16x8 o;
        o[0] = (bf16)v0.x; o[1] = (bf16)v0.y; o[2] = (bf16)v0.z; o[3] = (bf16)v0.w;
        o[4] = (bf16)v1.x; o[5] = (bf16)v1.y; o[6] = (bf16)v1.z; o[7] = (bf16)v1.w;
        *reinterpret_cast<bf16x8*>(&tile[r][tx * 8]) = o;
        *reinterpret_cast<bf16x8*>(outD + (size_t)(r0 + r) * Nn + c0 + tx * 8) = o;
    }
    __syncthreads();
    int c = t >> 2;               // local col -> output row
    int rsb = (t & 3) * 16;       // 16 source rows per thread
#pragma unroll
    for (int j = 0; j < 2; ++j) {
        int r = rsb + j * 8;
        bf16x8 o;
#pragma unroll
        for (int e = 0; e < 8; ++e) o[e] = tile[r + e][c];
        *reinterpret_cast<bf16x8*>(outT + (size_t)(c0 + c) * Nn + r0 + r) = o;
    }
}

// ---------- bf16 transpose: out[c][r] = in[r][c], dims multiple of 32 ----------
__global__ void transpose_bf16(const bf16* __restrict__ in, bf16* __restrict__ out,
                               int R, int C) {
    __shared__ bf16 tile[32][33];
    int c0 = blockIdx.x * 32, r0 = blockIdx.y * 32;
    int tx = threadIdx.x, ty = threadIdx.y;
    for (int i = ty; i < 32; i += 8)
        tile[i][tx] = in[(size_t)(r0 + i) * C + c0 + tx];
    __syncthreads();
    for (int i = ty; i < 32; i += 8)
        out[(size_t)(c0 + i) * R + r0 + tx] = tile[tx][i];
}

// ---------- NT GEMM: C[M,N] = A[M,K] * B[N,K]^T ----------
// m97 fragment layout + depth-2 software pipeline (3 LDS buffers, counted vmcnt)
// + T2 both-sides LDS swizzle: 16B slot s' = s ^ ((row>>1)&3) within each 16-row
// staging chunk. Applied at the global SOURCE (gll16 writes LDS linearly) and at
// the fragment READ -- same involution both sides (G21).
// OMODE: 0 = fp32 out at Cp + z*M*N; 1 = bf16 out; 2 = bf16 partial at Cp + z*M*N
template<int OMODE, bool HAS_BIAS, bool ROW_SCALE>
__global__ __launch_bounds__(256)
void gemm_nt(const bf16* __restrict__ A, const bf16* __restrict__ B,
             void* __restrict__ Cp, const float* __restrict__ bias,
             const float* __restrict__ rowscale, int M, int N, int K) {
    __shared__ __align__(16) bf16 As[3][128 * 32];
    __shared__ __align__(16) bf16 Bs[3][128 * 32];
    const int tid  = threadIdx.x;
    const int wave = tid >> 6;
    const int lane = tid & 63;
    const int m0 = blockIdx.y * 128, n0 = blockIdx.x * 128;
    const int lrow = lane >> 2;
    // swizzled source column: slot (lane&3) in LDS must hold logical slot (lane&3)^k(row),
    // k(row) = (row>>1)&3, row = lane>>2  =>  k = (lane>>3)&3
    const int lcol = ((lane & 3) ^ ((lane >> 3) & 3)) * 8;
    const int c0 = wave * 2;
    const size_t arow0 = (size_t)(m0 + c0 * 16 + lrow) * K + lcol;
    const size_t arow1 = (size_t)(m0 + (c0 + 1) * 16 + lrow) * K + lcol;
    const size_t brow0 = (size_t)(n0 + c0 * 16 + lrow) * K + lcol;
    const size_t brow1 = (size_t)(n0 + (c0 + 1) * 16 + lrow) * K + lcol;

    f32x4 acc[4][4] = {};

    const int wm = (wave >> 1) * 64;
    const int wn = (wave & 1) * 64;
    const int fm = wm + (lane & 15);
    const int fn = wn + (lane & 15);
    // swizzled read slot: want logical slot (lane>>4) of row (lane&15):
    // physical slot = (lane>>4) ^ ((row>>1)&3), row bits from lane&15 => (lane>>1)&3
    const int fk = ((lane >> 4) ^ ((lane >> 1) & 3)) * 8;

    const int kper = K / gridDim.z;
    const int kz0 = blockIdx.z * kper;
    const int nt = kper >> 5;

    auto stage = [&](int t, int buf) {
        const int k0 = kz0 + (t << 5);
        gll16(A + arow0 + k0, &As[buf][c0 * 512]);
        gll16(A + arow1 + k0, &As[buf][(c0 + 1) * 512]);
        gll16(B + brow0 + k0, &Bs[buf][c0 * 512]);
        gll16(B + brow1 + k0, &Bs[buf][(c0 + 1) * 512]);
    };

    // prologue: tiles 0 and 1 in flight (8 outstanding vmem ops per wave)
    stage(0, 0);
    if (nt > 1) stage(1, 1);

    int cur = 0;
    for (int t = 0; t < nt; ++t) {
        // wait for tile t only (tile t+1's 4 loads stay in flight)
        if (t + 1 < nt) asm volatile("s_waitcnt vmcnt(4)" ::: "memory");
        else            asm volatile("s_waitcnt vmcnt(0)" ::: "memory");
        __builtin_amdgcn_s_barrier();
        // issue tile t+2 into the buffer freed at the barrier above
        if (t + 2 < nt) {
            int nb = cur + 2; if (nb >= 3) nb -= 3;
            stage(t + 2, nb);
        }
        bf16x8 af[4], bg[4];
#pragma unroll
        for (int i = 0; i < 4; ++i)
            af[i] = *reinterpret_cast<const bf16x8*>(&As[cur][(fm + i * 16) * 32 + fk]);
#pragma unroll
        for (int j = 0; j < 4; ++j)
            bg[j] = *reinterpret_cast<const bf16x8*>(&Bs[cur][(fn + j * 16) * 32 + fk]);
#pragma unroll
        for (int i = 0; i < 4; ++i)
#pragma unroll
            for (int j = 0; j < 4; ++j)
                acc[i][j] = __builtin_amdgcn_mfma_f32_16x16x32_bf16(af[i], bg[j], acc[i][j], 0, 0, 0);
        cur = (cur + 1 == 3) ? 0 : cur + 1;
    }

    const int rbase = m0 + wm + (lane >> 4) * 4;
    const int cbase = n0 + wn + (lane & 15);
    float* outf = (float*)Cp + (size_t)blockIdx.z * M * N;
    bf16*  outb = (bf16*)Cp;
    bf16*  outp = (bf16*)Cp + (size_t)blockIdx.z * M * N;
#pragma unroll
    for (int i = 0; i < 4; ++i) {
#pragma unroll
        for (int j = 0; j < 4; ++j) {
            int col = cbase + j * 16;
            float bv = 0.f;
            if (HAS_BIAS) bv = bias[col];
#pragma unroll
            for (int r = 0; r < 4; ++r) {
                int row = rbase + i * 16 + r;
                float v = acc[i][j][r];
                if (ROW_SCALE) v *= rowscale[row];
                v += bv;
                if (OMODE == 0)      outf[(size_t)row * N + col] = v;
                else if (OMODE == 1) outb[(size_t)row * N + col] = (bf16)v;
                else                 outp[(size_t)row * N + col] = (bf16)v;
            }
        }
    }
}

// ---------- colnorm partials: n2[i] += sum_{a in chunk} (Rf0+Rf1)[a,i]*Ht[a,i] ----------
__global__ void colnorm_part(const bf16* __restrict__ Ht, const float* __restrict__ Rf,
                             float* __restrict__ n2) {
    int i = blockIdx.x * 128 + threadIdx.x;   // 32 x-blocks cover 4096 cols
    int a0 = blockIdx.y * 64;                 // 8 y-blocks cover 512 rows
    const float* Rf2 = Rf + (size_t)HIDD * NN;
    float s = 0.f;
    for (int a = a0; a < a0 + 64; ++a) {
        size_t idx = (size_t)a * NN + i;
        s += (Rf[idx] + Rf2[idx]) * (float)Ht[idx];
    }
    atomicAdd(&n2[i], s);
}

__global__ void colnorm_fin(const float* __restrict__ n2, float* __restrict__ inv) {
    int i = blockIdx.x * 256 + threadIdx.x;
    inv[i] = 1.f / fmaxf(sqrtf(n2[i]), 1e-12f);
}

// ---------- b' = W1 @ b0 + b1  (one wave per row) ----------
__global__ void bias_fuse(const float* __restrict__ W1, const float* __restrict__ b0,
                          const float* __restrict__ b1, float* __restrict__ bp) {
    int row = blockIdx.x * 4 + (threadIdx.x >> 6);
    int lane = threadIdx.x & 63;
    const float4* wr = (const float4*)(W1 + (size_t)row * HIDD);
    const float4* bz = (const float4*)b0;
    float s = 0.f;
#pragma unroll
    for (int j = 0; j < 2; ++j) {
        float4 a = wr[lane * 2 + j], b = bz[lane * 2 + j];
        s += a.x * b.x + a.y * b.y + a.z * b.z + a.w * b.w;
    }
    for (int off = 32; off; off >>= 1) s += __shfl_down(s, off);
    if (lane == 0) bp[row] = b1[row] + s;
}

// ---------- reduce 2 bf16 slices + rowscale + colbias -> bf16 (h epilogue) ----------
__global__ void reduce2_scale_bias(const bf16* __restrict__ p, bf16* __restrict__ out,
                                   const float* __restrict__ inv, const float* __restrict__ bp) {
    int i = (blockIdx.x * 256 + threadIdx.x) * 8;
    const int n = NN * HIDD;
    bf16x8 a = *reinterpret_cast<const bf16x8*>(p + i);
    bf16x8 b = *reinterpret_cast<const bf16x8*>(p + n + i);
    int row = i >> 9;           // HIDD = 512
    int col = i & (HIDD - 1);
    float sc = inv[row];
    bf16x8 o;
#pragma unroll
    for (int j = 0; j < 8; ++j)
        o[j] = (bf16)(((float)a[j] + (float)b[j]) * sc + bp[col + j]);
    *reinterpret_cast<bf16x8*>(out + i) = o;
}

// ---------- CSR build ----------
__global__ void csr_count(const int* __restrict__ ei, int* __restrict__ cnt, int E) {
    int e = blockIdx.x * 256 + threadIdx.x;
    if (e < E) atomicAdd(&cnt[ei[e]], 1);
}

__global__ void scan_4096(const int* __restrict__ cnt, int* __restrict__ rs) {
    __shared__ int s[1024];
    int t = threadIdx.x;
    int b = t * 4;
    int a0 = cnt[b], a1 = cnt[b + 1], a2 = cnt[b + 2], a3 = cnt[b + 3];
    int tot = a0 + a1 + a2 + a3;
    s[t] = tot;
    __syncthreads();
    for (int off = 1; off < 1024; off <<= 1) {
        int v = (t >= off) ? s[t - off] : 0;
        __syncthreads();
        s[t] += v;
        __syncthreads();
    }
    int excl = s[t] - tot;
    rs[b] = excl; rs[b + 1] = excl + a0; rs[b + 2] = excl + a0 + a1; rs[b + 3] = excl + a0 + a1 + a2;
    if (t == 1023) rs[4096] = s[1023];
}

__global__ void csr_scatter(const int* __restrict__ ei, const float* __restrict__ ew,
                            int* __restrict__ cur, int* __restrict__ ccol,
                            float* __restrict__ cw, int E) {
    int e = blockIdx.x * 256 + threadIdx.x;
    if (e < E) {
        int r = ei[e];
        int p = atomicAdd(&cur[r], 1);
        ccol[p] = ei[E + e];
        cw[p] = ew[e];
    }
}

// ---------- one Euler diffusion step in bf16: x' = x + alpha*(Ax - x) + beta*x0 ----------
__global__ void ode_step_bf16(const bf16* __restrict__ xin, const bf16* __restrict__ x0,
                              bf16* __restrict__ xout, const int* __restrict__ rs,
                              const int* __restrict__ ccol, const float* __restrict__ cw,
                              const float* __restrict__ alpha_p, const float* __restrict__ beta_p) {
    int row = blockIdx.x * 4 + (threadIdx.x >> 6);
    int lane = threadIdx.x & 63;
    float alpha = 1.f / (1.f + expf(-alpha_p[0]));
    float beta = beta_p[0];
    const bf16x8* xin8 = (const bf16x8*)xin;
    float acc[8] = {};
    int p0 = rs[row], p1 = rs[row + 1];
    for (int p = p0; p < p1; ++p) {
        int c = ccol[p]; float w = cw[p];
        bf16x8 v = xin8[(size_t)c * 64 + lane];
#pragma unroll
        for (int j = 0; j < 8; ++j) acc[j] += w * (float)v[j];
    }
    bf16x8 xi = xin8[(size_t)row * 64 + lane];
    bf16x8 xz = ((const bf16x8*)x0)[(size_t)row * 64 + lane];
    bf16x8 r;
#pragma unroll
    for (int j = 0; j < 8; ++j) {
        float x = (float)xi[j];
        r[j] = (bf16)(x + alpha * (acc[j] - x) + beta * (float)xz[j]);
    }
    ((bf16x8*)xout)[(size_t)row * 64 + lane] = r;
}

// ---------- epilogue 1: z = relu(nf*x8 + h); column sums + global sum/sumsq ----------
__global__ void epi1(const bf16* __restrict__ x8, const bf16* __restrict__ h,
                     const float* __restrict__ nf_p, float* __restrict__ z,
                     float* __restrict__ colsum, float* __restrict__ gst) {
    __shared__ float r1[512], r2[512];
    int b = blockIdx.x, j = threadIdx.x;   // 512 threads, 8 rows/block
    float nf = nf_p[0];
    float cp = 0.f, sq = 0.f;
    for (int i = 0; i < 8; ++i) {
        size_t idx = (size_t)(b * 8 + i) * HIDD + j;
        float v = nf * (float)x8[idx] + (float)h[idx];
        v = fmaxf(v, 0.f);
        z[idx] = v;
        cp += v; sq += v * v;
    }
    atomicAdd(&colsum[j], cp);
    r1[j] = cp; r2[j] = sq;
    __syncthreads();
    for (int off = 256; off > 0; off >>= 1) {
        if (j < off) { r1[j] += r1[j + off]; r2[j] += r2[j + off]; }
        __syncthreads();
    }
    if (j == 0) { atomicAdd(&gst[0], r1[0]); atomicAdd(&gst[1], r2[0]); }
}

// ---------- epilogue 2: out = (z - colmean) / global_std(ddof=1), fp32 ----------
__global__ void epi2(const float* __restrict__ z, const float* __restrict__ colsum,
                     const float* __restrict__ gst, float* __restrict__ out) {
    size_t idx = (size_t)blockIdx.x * 256 + threadIdx.x;
    int j = (int)(idx & (HIDD - 1));
    float n = (float)NN * (float)HIDD;
    float gmean = gst[0] / n;
    float var = (gst[1] - n * gmean * gmean) / (n - 1.f);
    float istd = rsqrtf(var);
    float mean = colsum[j] * (1.f / (float)NN);
    out[idx] = (z[idx] - mean) * istd;
}

extern "C" void kernel_launch(void* const* d_in, const int* in_sizes, int n_in,
                              void* d_out, int out_size, void* d_ws, size_t ws_size,
                              hipStream_t stream) {
    const float* knn  = (const float*)d_in[0];
    const float* adj  = (const float*)d_in[1];
    const float* nf   = (const float*)d_in[2];
    const float* w1   = (const float*)d_in[3];
    const float* w2   = (const float*)d_in[4];
    const float* W0   = (const float*)d_in[5];
    const float* b0   = (const float*)d_in[6];
    const float* W1   = (const float*)d_in[7];
    const float* b1   = (const float*)d_in[8];
    const float* ew   = (const float*)d_in[9];
    const float* alph = (const float*)d_in[10];
    const float* beta = (const float*)d_in[11];
    const int*   ei   = (const int*)d_in[12];

    char* w = (char*)d_ws;
    size_t off = 0;
    auto alloc = [&](size_t bytes) -> char* {
        char* p = w + off;
        off += (bytes + 255) & ~(size_t)255;
        return p;
    };
    const size_t SZ_NN  = (size_t)NN * NN * sizeof(bf16);      // 32 MiB
    const size_t SZ_TH  = (size_t)HIDD * NN * sizeof(bf16);    // 4 MiB
    bf16* Bar  = (bf16*)alloc(SZ_NN);                 // adjT
    bf16* Car  = (bf16*)alloc(SZ_NN);                 // w2b -> w1b -> W0b / W1b -> ODE x
    bf16* Adjb = (bf16*)alloc(SZ_NN);                 // adj bf16 (straight)
    bf16* knnT = (bf16*)alloc(SZ_TH);
    bf16* tA   = (bf16*)alloc(SZ_TH);
    bf16* tB   = (bf16*)alloc(SZ_TH);                 // ends as H^T
    float* tf  = (float*)alloc((size_t)32 * 1024 * 1024);  // partials / Rf fp32 / z fp32
    bf16* Hm   = (bf16*)alloc(SZ_TH);                 // H [4096,512]
    bf16* Gb   = (bf16*)alloc((size_t)HIDD * HIDD * sizeof(bf16));
    bf16* M0b  = (bf16*)alloc((size_t)HIDD * HIDD * sizeof(bf16));
    bf16* Qtb  = (bf16*)alloc((size_t)HIDD * HIDD * sizeof(bf16));
    bf16* hb   = (bf16*)alloc((size_t)NN * HIDD * sizeof(bf16));  // h in bf16
    float* inv = (float*)alloc(NN * sizeof(float));
    float* n2  = (float*)alloc(NN * sizeof(float));
    int*  cnt  = (int*)alloc(NN * sizeof(int));
    int*  rs   = (int*)alloc((NN + 1) * sizeof(int));
    int*  cur  = (int*)alloc(NN * sizeof(int));
    int*  ccol = (int*)alloc(NE * sizeof(int));
    float* cw  = (float*)alloc(NE * sizeof(float));
    float* colsum = (float*)alloc(HIDD * sizeof(float));
    float* gst = (float*)alloc(2 * sizeof(float));
    float* bp  = (float*)alloc(HIDD * sizeof(float));
    bf16* tfb = (bf16*)tf;                            // bf16 partial view of tf
    bf16* W1b = (bf16*)((char*)Car + 16 * 1024 * 1024);
    bf16* xA  = (bf16*)Car;                           // 4 MiB (W0b dead by then)
    bf16* xB  = (bf16*)Car + (size_t)NN * HIDD;       // next 4 MiB
    (void)ws_size; (void)n_in; (void)in_sizes; (void)out_size;

    dim3 tb(32, 8);
    const int nTH = HIDD * NN;      // 2M elems
    const int nHH = HIDD * HIDD;    // 256K elems

    // ---- prep ----
    transpose_pad_f32<<<dim3(16, 128), tb, 0, stream>>>(knn, knnT, NN, 500, HIDD);
    cvt_f32_bf16<<<(NN * NN) / 1024, 256, 0, stream>>>(w2, Car, NN * NN);
    transpose_dual_f32<<<dim3(64, 64), 256, 0, stream>>>(adj, Bar, Adjb, NN);

    // ---- chain (transposed): t1^T=knn^T w2^T ; t2^T=t1^T adj ; t3^T=t2^T w1^T ; H^T=t3^T adj^T
    // NT with B = {w2, adjT, w1, adj}; split-K=4 bf16 partials in tf, deterministic reduce.
    gemm_nt<2, false, false><<<dim3(32, 4, 4), 256, 0, stream>>>(knnT, Car, tfb, nullptr, nullptr, HIDD, NN, NN);
    reduce_bf16_slices<<<nTH / 2048, 256, 0, stream>>>(tfb, tA, nTH, 4);
    gemm_nt<2, false, false><<<dim3(32, 4, 4), 256, 0, stream>>>(tA, Bar, tfb, nullptr, nullptr, HIDD, NN, NN);
    reduce_bf16_slices<<<nTH / 2048, 256, 0, stream>>>(tfb, tB, nTH, 4);
    cvt_f32_bf16<<<(NN * NN) / 1024, 256, 0, stream>>>(w1, Car, NN * NN);
    gemm_nt<2, false, false><<<dim3(32, 4, 4), 256, 0, stream>>>(tB, Car, tfb, nullptr, nullptr, HIDD, NN, NN);
    reduce_bf16_slices<<<nTH / 2048, 256, 0, stream>>>(tfb, tA, nTH, 4);
    gemm_nt<2, false, false><<<dim3(32, 4, 4), 256, 0, stream>>>(tA, Adjb, tfb, nullptr, nullptr, HIDD, NN, NN);
    reduce_bf16_slices<<<nTH / 2048, 256, 0, stream>>>(tfb, tB, nTH, 4);   // tB = H^T

    // ---- H [4096,512] ----
    transpose_bf16<<<dim3(128, 16), tb, 0, stream>>>(tB, Hm, HIDD, NN);

    // ---- G = H^T H  [512,512], split-K=32 ----
    gemm_nt<2, false, false><<<dim3(4, 4, 32), 256, 0, stream>>>(tB, tB, tfb, nullptr, nullptr, HIDD, HIDD, NN);
    reduce_bf16_slices<<<nHH / 2048, 256, 0, stream>>>(tfb, Gb, nHH, 32);

    // ---- R^T = G H^T  [512,4096] fp32, split-K=2 (K=512) ----
    gemm_nt<0, false, false><<<dim3(32, 4, 2), 256, 0, stream>>>(Gb, Hm, tf, nullptr, nullptr, HIDD, NN, HIDD);
    // ---- norms: inv[i] = 1/max(sqrt(sum_a (R^T slices)[a,i]*H^T[a,i]), 1e-12) ----
    hipMemsetAsync(n2, 0, NN * sizeof(float), stream);
    colnorm_part<<<dim3(32, 8), 128, 0, stream>>>(tB, tf, n2);
    colnorm_fin<<<NN / 256, 256, 0, stream>>>(n2, inv);

    // ---- M0 = H^T W0^T  [512,512], split-K=32 ----
    cvt_f32_bf16<<<(HIDD * NN) / 1024, 256, 0, stream>>>(W0, Car, HIDD * NN);
    gemm_nt<2, false, false><<<dim3(4, 4, 32), 256, 0, stream>>>(tB, Car, tfb, nullptr, nullptr, HIDD, HIDD, NN);
    reduce_bf16_slices<<<nHH / 2048, 256, 0, stream>>>(tfb, M0b, nHH, 32);

    // ---- Q^T = W1 M0^T  [512,512], split-K=8 (K=512) ----
    cvt_f32_bf16<<<(HIDD * HIDD) / 1024, 256, 0, stream>>>(W1, W1b, HIDD * HIDD);
    gemm_nt<2, false, false><<<dim3(4, 4, 8), 256, 0, stream>>>(W1b, M0b, tfb, nullptr, nullptr, HIDD, HIDD, HIDD);
    reduce_bf16_slices<<<nHH / 2048, 256, 0, stream>>>(tfb, Qtb, nHH, 8);

    // ---- b' = W1 b0 + b1 ----
    bias_fuse<<<128, 256, 0, stream>>>(W1, b0, b1, bp);

    // ---- h = diag(inv) H Q + b'  [4096,512] bf16, split-K=2 (K=512) ----
    gemm_nt<2, false, false><<<dim3(4, 32, 2), 256, 0, stream>>>(Hm, Qtb, tfb, nullptr, nullptr, NN, HIDD, HIDD);
    reduce2_scale_bias<<<(NN * HIDD) / 2048, 256, 0, stream>>>(tfb, hb, inv, bp);

    // ---- CSR build ----
    hipMemsetAsync(cnt, 0, NN * sizeof(int), stream);
    csr_count<<<NE / 256, 256, 0, stream>>>(ei, cnt, NE);
    scan_4096<<<1, 1024, 0, stream>>>(cnt, rs);
    hipMemcpyAsync(cur, rs, NN * sizeof(int), hipMemcpyDeviceToDevice, stream);
    csr_scatter<<<NE / 256, 256, 0, stream>>>(ei, ew, cur, ccol, cw, NE);

    // ---- 8 Euler steps (bf16 state): hb -> xA -> xB -> ... -> final in xB ----
    const bf16* xi = hb;
    bf16* xo = xA;
    for (int s = 0; s < 8; ++s) {
        ode_step_bf16<<<NN / 4, 256, 0, stream>>>(xi, hb, xo, rs, ccol, cw, alph, beta);
        xi = xo;
        xo = (s % 2 == 0) ? xB : xA;
    }

    // ---- epilogue ----
    hipMemsetAsync(colsum, 0, HIDD * sizeof(float), stream);
    hipMemsetAsync(gst, 0, 2 * sizeof(float), stream);
    epi1<<<NN / 8, 512, 0, stream>>>(xB, hb, nf, tf, colsum, gst);
    epi2<<<(NN * HIDD) / 256, 256, 0, stream>>>(tf, colsum, gst, (float*)d_out);
}